// Round 4
// baseline (3530.735 us; speedup 1.0000x reference)
//
#include <hip/hip_runtime.h>
#include <math.h>

#define NB 64       // batch
#define NT 128      // time steps
#define NE 64       // embedding
#define NU 512      // units
#define NG 2048     // 4*U
#define NV 2000     // vocab
#define BU (NB*NU)
#define GRID_LSTM 256

typedef __attribute__((ext_vector_type(8))) short bf16x8;
typedef __attribute__((ext_vector_type(4))) float f32x4;
typedef __attribute__((ext_vector_type(8))) unsigned short u16x8;

__device__ __forceinline__ unsigned short f2bf(float x) {
    // round-to-nearest-even fp32 -> bf16 (bit-level, no struct dependence)
    unsigned int u = __float_as_uint(x);
    u += 0x7FFFu + ((u >> 16) & 1u);
    return (unsigned short)(u >> 16);
}

__device__ __forceinline__ float fsigmoid(float x) {
    return __builtin_amdgcn_rcpf(1.f + __expf(-x));
}
__device__ __forceinline__ float ftanh(float x) {
    // 1 - 2/(exp(2x)+1); exp overflow -> inf -> rcp -> 0 -> 1 (graceful)
    return 1.f - 2.f * __builtin_amdgcn_rcpf(__expf(2.f * x) + 1.f);
}

// ---------------------------------------------------------------------------
// Cooperative LSTM: 256 blocks x 512 threads, split into 8 INDEPENDENT groups
// of 32 blocks (group rg = bk&7 owns batch rows 8rg..8rg+7; cgi = bk>>3 owns
// units u0..u0+16). Wave wv owns k-slice [64wv,64wv+64). Wh in VGPRs.
// Sync per step: waves 0/1 publish h via agent-scope relaxed atomics, wait
// vmcnt(0), then store flag[rg][half][cgi]=t+1 (contention-free: one slot per
// writer, plain stores not RMW). Every wave polls its group's 64 flags
// (coalesced 64-lane load + min-butterfly) then reloads exactly the h slice
// it consumes (no second __syncthreads; psum is double-buffered so fast waves
// can run one step ahead safely).
// ---------------------------------------------------------------------------
__global__ __launch_bounds__(512, 1)
void lstm_coop(const float* __restrict__ emb, const int* __restrict__ ids,
               const float* __restrict__ Wx, const float* __restrict__ Wh,
               const float* __restrict__ bias,
               const float* __restrict__ h0, const float* __restrict__ c0,
               float* __restrict__ Hout, float* __restrict__ hping,
               float* __restrict__ cfin, unsigned int* __restrict__ flags)
{
    __shared__ float psum[2][8][8][64];        // 32 KB, parity = t&1
    __shared__ float hlds[8][512];             // 16 KB

    const int tid  = threadIdx.x;
    const int wv   = tid >> 6;                 // 0..7 k-slice
    const int cl   = tid & 63;
    const int bk   = blockIdx.x;
    const int rg   = bk & 7;                   // group (8 groups x 32 blocks)
    const int cgi  = bk >> 3;                  // 0..31 unit slice
    const int brow0 = rg * 8;
    const int u0    = cgi * 16;
    const int gate  = cl >> 4;
    const int uu_c  = cl & 15;
    const int colg  = gate * 512 + u0 + uu_c;

    float w[64];
#pragma unroll
    for (int kk = 0; kk < 64; ++kk) w[kk] = Wh[(size_t)(wv * 64 + kk) * NG + colg];
    float wx[8];
#pragma unroll
    for (int ee = 0; ee < 8; ++ee) wx[ee] = Wx[(size_t)(wv * 8 + ee) * NG + colg];

    const int bl  = tid >> 4;                  // tid<128: row
    const int uug = tid & 15;
    float creg = 0.f;
    float b4[4] = {0.f, 0.f, 0.f, 0.f};
    if (tid < 128) {
#pragma unroll
        for (int g = 0; g < 4; ++g) b4[g] = bias[g * 512 + u0 + uug];
        if (c0) creg = c0[(brow0 + bl) * NU + u0 + uug];
    }

    // stage h(0): each wave stages exactly its k-slice (cols 64wv..64wv+63)
    {
        const int col = wv * 64 + cl;
#pragma unroll
        for (int b = 0; b < 8; ++b)
            hlds[b][col] = h0 ? h0[(brow0 + b) * NU + col] : 0.f;
    }
    unsigned int* fl = flags + rg * 64;

    for (int t = 0; t < NT; ++t) {
        // ---- z partial: own k-slice from hlds (written by this wave)
        float acc[8];
#pragma unroll
        for (int b = 0; b < 8; ++b) {
            const float4* hb4 = reinterpret_cast<const float4*>(&hlds[b][wv * 64]);
            float a0 = 0.f, a1 = 0.f, a2 = 0.f, a3 = 0.f;
#pragma unroll
            for (int k4 = 0; k4 < 16; k4 += 4) {
                float4 v0 = hb4[k4 + 0];
                a0 += v0.x * w[4 * k4 + 0] + v0.y * w[4 * k4 + 1] + v0.z * w[4 * k4 + 2] + v0.w * w[4 * k4 + 3];
                float4 v1 = hb4[k4 + 1];
                a1 += v1.x * w[4 * k4 + 4] + v1.y * w[4 * k4 + 5] + v1.z * w[4 * k4 + 6] + v1.w * w[4 * k4 + 7];
                float4 v2 = hb4[k4 + 2];
                a2 += v2.x * w[4 * k4 + 8] + v2.y * w[4 * k4 + 9] + v2.z * w[4 * k4 + 10] + v2.w * w[4 * k4 + 11];
                float4 v3 = hb4[k4 + 3];
                a3 += v3.x * w[4 * k4 + 12] + v3.y * w[4 * k4 + 13] + v3.z * w[4 * k4 + 14] + v3.w * w[4 * k4 + 15];
            }
            const int idb = ids[(brow0 + b) * NT + t];
            const float4* eb = reinterpret_cast<const float4*>(emb + (size_t)idb * NE + wv * 8);
            float4 e0 = eb[0], e1 = eb[1];
            a0 += e0.x * wx[0] + e0.y * wx[1] + e0.z * wx[2] + e0.w * wx[3];
            a1 += e1.x * wx[4] + e1.y * wx[5] + e1.z * wx[6] + e1.w * wx[7];
            acc[b] = (a0 + a1) + (a2 + a3);
        }
        const int par = t & 1;
#pragma unroll
        for (int b = 0; b < 8; ++b) psum[par][wv][b][cl] = acc[b];
        __syncthreads();                       // the ONLY block barrier per step

        if (tid < 128) {
            float z[4];
#pragma unroll
            for (int g = 0; g < 4; ++g) {
                float s = b4[g];
#pragma unroll
                for (int w8 = 0; w8 < 8; ++w8) s += psum[par][w8][bl][g * 16 + uug];
                z[g] = s;
            }
            const float i_ = fsigmoid(z[0]);
            const float f_ = fsigmoid(z[1]);
            const float g_ = ftanh(z[2]);
            const float o_ = fsigmoid(z[3]);
            creg = f_ * creg + i_ * g_;
            const float h_ = o_ * ftanh(creg);
            const int row = brow0 + bl;
            float* hw = hping + ((t + 1) & 1) * BU;
            __hip_atomic_store(&hw[row * NU + u0 + uug], h_,
                               __ATOMIC_RELAXED, __HIP_MEMORY_SCOPE_AGENT);
            Hout[((size_t)row * NT + t) * NU + u0 + uug] = h_;
        }
        if (t == NT - 1) break;

        // ---- publish: per-writer flag slot (no RMW contention)
        if (tid < 128) {
            asm volatile("s_waitcnt vmcnt(0)" ::: "memory");
            if ((tid & 63) == 0)
                __hip_atomic_store(&fl[(tid >> 6) * 32 + cgi], (unsigned)(t + 1),
                                   __ATOMIC_RELAXED, __HIP_MEMORY_SCOPE_AGENT);
        }

        // ---- every wave polls its group's 64 flags independently
        {
            const unsigned target = (unsigned)(t + 1);
            while (true) {
                unsigned v = __hip_atomic_load(&fl[cl], __ATOMIC_RELAXED,
                                               __HIP_MEMORY_SCOPE_AGENT);
#pragma unroll
                for (int o = 32; o; o >>= 1) {
                    unsigned v2 = (unsigned)__shfl_xor((int)v, o);
                    v = v2 < v ? v2 : v;
                }
                if (v >= target) break;
                __builtin_amdgcn_s_sleep(1);
            }
            asm volatile("" ::: "memory");
        }

        // ---- reload own h slice (coalesced agent loads), write own LDS cols
        {
            const float* hr = hping + ((t + 1) & 1) * BU + (size_t)brow0 * NU;
            const int col = wv * 64 + cl;
            float tmp[8];
#pragma unroll
            for (int b = 0; b < 8; ++b)
                tmp[b] = __hip_atomic_load(const_cast<float*>(&hr[b * NU + col]),
                                           __ATOMIC_RELAXED, __HIP_MEMORY_SCOPE_AGENT);
#pragma unroll
            for (int b = 0; b < 8; ++b) hlds[b][col] = tmp[b];
        }
    }
    if (tid < 128) cfin[(brow0 + bl) * NU + u0 + uug] = creg;
}

// ---------------------------------------------------------------------------
// Attention: one wave per (b,q), registers + butterflies.
// ---------------------------------------------------------------------------
__global__ __launch_bounds__(256)
void attn_kernel(const float* __restrict__ S, const float* __restrict__ Hbuf,
                 const float* __restrict__ s0, float* __restrict__ A)
{
    const int tid  = threadIdx.x;
    const int wv   = tid >> 6;
    const int lane = tid & 63;
    const int b    = blockIdx.x >> 5;
    const int q    = (blockIdx.x & 31) * 4 + wv;

    const float* qrow = (q == 0) ? (s0 + (size_t)b * NU)
                                 : (S + ((size_t)b * NT + (q - 1)) * NU);
    const float4* q4 = reinterpret_cast<const float4*>(qrow);
    const float4 qa = q4[lane], qb = q4[64 + lane];
    const float4* Hb = reinterpret_cast<const float4*>(Hbuf + (size_t)b * NT * NU);

    float sr0 = 0.f, sr1 = 0.f;
    for (int k = 0; k < NT; ++k) {
        const float4* hk = Hb + (size_t)k * 128;
        float4 ha = hk[lane], hc = hk[64 + lane];
        float d = qa.x * ha.x + qa.y * ha.y + qa.z * ha.z + qa.w * ha.w
                + qb.x * hc.x + qb.y * hc.y + qb.z * hc.z + qb.w * hc.w;
#pragma unroll
        for (int o = 32; o; o >>= 1) d += __shfl_xor(d, o);
        if ((k & 63) == lane) { if (k < 64) sr0 = d; else sr1 = d; }
        if ((k & 31) == 31) __syncthreads();
    }

    float m = fmaxf(sr0, sr1);
#pragma unroll
    for (int o = 32; o; o >>= 1) m = fmaxf(m, __shfl_xor(m, o));
    float e0 = expf(sr0 - m), e1 = expf(sr1 - m);
    float s = e0 + e1;
#pragma unroll
    for (int o = 32; o; o >>= 1) s += __shfl_xor(s, o);
    const float inv = 1.f / s;
    e0 *= inv; e1 *= inv;

    float4 acc0 = {0.f, 0.f, 0.f, 0.f}, acc1 = {0.f, 0.f, 0.f, 0.f};
    for (int k = 0; k < 64; ++k) {
        const float wk = __shfl(e0, k);
        const float4* hk = Hb + (size_t)k * 128;
        float4 ha = hk[lane], hc = hk[64 + lane];
        acc0.x += wk * ha.x; acc0.y += wk * ha.y; acc0.z += wk * ha.z; acc0.w += wk * ha.w;
        acc1.x += wk * hc.x; acc1.y += wk * hc.y; acc1.z += wk * hc.z; acc1.w += wk * hc.w;
        if ((k & 31) == 31) __syncthreads();
    }
    for (int k = 0; k < 64; ++k) {
        const float wk = __shfl(e1, k);
        const float4* hk = Hb + (size_t)(64 + k) * 128;
        float4 ha = hk[lane], hc = hk[64 + lane];
        acc0.x += wk * ha.x; acc0.y += wk * ha.y; acc0.z += wk * ha.z; acc0.w += wk * ha.w;
        acc1.x += wk * hc.x; acc1.y += wk * hc.y; acc1.z += wk * hc.z; acc1.w += wk * hc.w;
        if ((k & 31) == 31) __syncthreads();
    }
    float4* Aq = reinterpret_cast<float4*>(A + ((size_t)b * NT + q) * NU);
    Aq[lane] = acc0;
    Aq[64 + lane] = acc1;
}

// ---------------------------------------------------------------------------
// Convert yo=[S|A] (fp32) -> bf16 [8192][1024] (aliases Hbuf; runs after attn)
// ---------------------------------------------------------------------------
__global__ __launch_bounds__(256)
void conv_yo(const float* __restrict__ S, const float* __restrict__ A,
             unsigned short* __restrict__ yo)
{
    const int base = (blockIdx.x * 256 + threadIdx.x) * 8;   // 8 elems/thread
    const int row = base >> 10;
    const int col = base & 1023;
    const float* src = (col < 512) ? (S + (size_t)row * NU + col)
                                   : (A + (size_t)row * NU + (col - 512));
    const float4 v0 = reinterpret_cast<const float4*>(src)[0];
    const float4 v1 = reinterpret_cast<const float4*>(src)[1];
    u16x8 o;
    o[0] = f2bf(v0.x); o[1] = f2bf(v0.y); o[2] = f2bf(v0.z); o[3] = f2bf(v0.w);
    o[4] = f2bf(v1.x); o[5] = f2bf(v1.y); o[6] = f2bf(v1.z); o[7] = f2bf(v1.w);
    *reinterpret_cast<u16x8*>(yo + base) = o;
}

// ---------------------------------------------------------------------------
// Transpose dense_W [1024][2000] fp32 -> Wt [2048][1024] bf16 (pad rows zero)
// ---------------------------------------------------------------------------
__global__ __launch_bounds__(256)
void conv_Wt(const float* __restrict__ W, unsigned short* __restrict__ Wt)
{
    __shared__ float lt[64][65];
    const int tid = threadIdx.x;
    const int c0 = blockIdx.x * 64;
    const int k0 = blockIdx.y * 64;
#pragma unroll
    for (int j = 0; j < 16; ++j) {
        const int lin = tid + 256 * j;
        const int kk = lin >> 6, cc = lin & 63;
        const int c = c0 + cc;
        lt[cc][kk] = (c < NV) ? W[(size_t)(k0 + kk) * NV + c] : 0.f;
    }
    __syncthreads();
    const int c = tid >> 2, kseg = tid & 3;
    unsigned short tmp[16];
#pragma unroll
    for (int m = 0; m < 16; ++m)
        tmp[m] = f2bf(lt[c][kseg * 16 + m]);
    unsigned short* dst = Wt + (size_t)(c0 + c) * 1024 + k0 + kseg * 16;
    *reinterpret_cast<u16x8*>(dst)     = *reinterpret_cast<u16x8*>(tmp);
    *reinterpret_cast<u16x8*>(dst + 8) = *reinterpret_cast<u16x8*>(tmp + 8);
}

// ---------------------------------------------------------------------------
// Dense via bf16 MFMA: out[8192][2000] = yo[8192][1024] x W[1024][2000] + b.
// 128x128 tile, 4 waves in 2x2, mfma_f32_16x16x32_bf16, +8 pad kills LDS
// read conflicts. Frags: A row=lane&15,k=(lane>>4)*8+j; B col=lane&15 (from
// transposed Wt); C col=lane&15,row=(lane>>4)*4+reg.
// ---------------------------------------------------------------------------
__global__ __launch_bounds__(256)
void dense_mfma(const unsigned short* __restrict__ yo,
                const unsigned short* __restrict__ Wt,
                const float* __restrict__ bias, float* __restrict__ out)
{
    __shared__ unsigned short Asm[128][40];
    __shared__ unsigned short Bsm[128][40];
    const int tid  = threadIdx.x;
    const int wave = tid >> 6, lane = tid & 63;
    const int wm = wave >> 1, wn = wave & 1;
    const int r0 = blockIdx.y * 128, c0 = blockIdx.x * 128;
    const int rr = lane & 15, kh = lane >> 4;

    f32x4 acc[4][4];
#pragma unroll
    for (int m = 0; m < 4; ++m)
#pragma unroll
        for (int n = 0; n < 4; ++n) acc[m][n] = (f32x4){0.f, 0.f, 0.f, 0.f};

    for (int k0 = 0; k0 < 1024; k0 += 32) {
        __syncthreads();
#pragma unroll
        for (int h = 0; h < 2; ++h) {
            const int row = (tid >> 2) + h * 64, seg = tid & 3;
            *reinterpret_cast<uint4*>(&Asm[row][seg * 8]) =
                *reinterpret_cast<const uint4*>(yo + (size_t)(r0 + row) * 1024 + k0 + seg * 8);
            *reinterpret_cast<uint4*>(&Bsm[row][seg * 8]) =
                *reinterpret_cast<const uint4*>(Wt + (size_t)(c0 + row) * 1024 + k0 + seg * 8);
        }
        __syncthreads();
        bf16x8 af[4], bfr[4];
#pragma unroll
        for (int m = 0; m < 4; ++m)
            af[m] = *reinterpret_cast<const bf16x8*>(&Asm[wm * 64 + m * 16 + rr][kh * 8]);
#pragma unroll
        for (int n = 0; n < 4; ++n)
            bfr[n] = *reinterpret_cast<const bf16x8*>(&Bsm[wn * 64 + n * 16 + rr][kh * 8]);
#pragma unroll
        for (int m = 0; m < 4; ++m)
#pragma unroll
            for (int n = 0; n < 4; ++n)
                acc[m][n] = __builtin_amdgcn_mfma_f32_16x16x32_bf16(af[m], bfr[n], acc[m][n], 0, 0, 0);
    }

#pragma unroll
    for (int m = 0; m < 4; ++m) {
#pragma unroll
        for (int n = 0; n < 4; ++n) {
            const int c = c0 + wn * 64 + n * 16 + rr;
            if (c < NV) {
                const float bc = bias[c];
#pragma unroll
                for (int reg = 0; reg < 4; ++reg) {
                    const int r = r0 + wm * 64 + m * 16 + kh * 4 + reg;
                    out[(size_t)r * NV + c] = acc[m][n][reg] + bc;
                }
            }
        }
    }
}

// ---------------------------------------------------------------------------
// In-place row softmax over V=2000 logits.
// ---------------------------------------------------------------------------
__global__ __launch_bounds__(256)
void softmax_rows(float* __restrict__ out)
{
    __shared__ float red[4];
    const int t = threadIdx.x;
    float* row = out + (size_t)blockIdx.x * NV;

    float v[8];
    float m = -INFINITY;
#pragma unroll
    for (int i = 0; i < 8; ++i) {
        const int j = t + 256 * i;
        v[i] = (j < NV) ? row[j] : -INFINITY;
        m = fmaxf(m, v[i]);
    }
#pragma unroll
    for (int o = 32; o; o >>= 1) m = fmaxf(m, __shfl_xor(m, o));
    if ((t & 63) == 0) red[t >> 6] = m;
    __syncthreads();
    m = fmaxf(fmaxf(red[0], red[1]), fmaxf(red[2], red[3]));
    __syncthreads();

    float s = 0.f;
#pragma unroll
    for (int i = 0; i < 8; ++i) {
        const int j = t + 256 * i;
        if (j < NV) { v[i] = expf(v[i] - m); s += v[i]; }
    }
#pragma unroll
    for (int o = 32; o; o >>= 1) s += __shfl_xor(s, o);
    if ((t & 63) == 0) red[t >> 6] = s;
    __syncthreads();
    const float inv = 1.f / (red[0] + red[1] + red[2] + red[3]);
#pragma unroll
    for (int i = 0; i < 8; ++i) {
        const int j = t + 256 * i;
        if (j < NV) row[j] = v[i] * inv;
    }
}

// ---------------------------------------------------------------------------
extern "C" void kernel_launch(void* const* d_in, const int* in_sizes, int n_in,
                              void* d_out, int out_size, void* d_ws, size_t ws_size,
                              hipStream_t stream)
{
    const int*   x       = (const int*)  d_in[0];
    const int*   y       = (const int*)  d_in[1];
    const float* enc_emb = (const float*)d_in[2];
    const float* enc_Wx  = (const float*)d_in[3];
    const float* enc_Wh  = (const float*)d_in[4];
    const float* enc_b   = (const float*)d_in[5];
    const float* dec_emb = (const float*)d_in[6];
    const float* dec_Wx  = (const float*)d_in[7];
    const float* dec_Wh  = (const float*)d_in[8];
    const float* dec_b   = (const float*)d_in[9];
    const float* dns_W   = (const float*)d_in[10];
    const float* dns_b   = (const float*)d_in[11];
    float* out = (float*)d_out;

    float* ws   = (float*)d_ws;
    float* Hbuf = ws;                                  // [B,T,U] fp32 (later aliased by yo bf16)
    float* Sbuf = Hbuf + (size_t)NB * NT * NU;
    float* Abuf = Sbuf + (size_t)NB * NT * NU;
    unsigned short* Wt = (unsigned short*)(Abuf + (size_t)NB * NT * NU);  // [2048][1024] bf16
    float* ehp  = (float*)(Wt + (size_t)2048 * 1024);  // enc h ping-pong [2][B,U]
    float* dhp  = ehp + 2 * BU;
    float* cfe  = dhp + 2 * BU;
    float* cfd  = cfe + BU;
    unsigned int* bar0 = (unsigned int*)(cfd + BU);    // 512 flags enc
    unsigned int* bar1 = bar0 + 512;                   // 512 flags dec
    unsigned short* yo = (unsigned short*)Hbuf;        // bf16 [8192][1024], alias

    hipMemsetAsync(bar0, 0, 2 * 512 * sizeof(unsigned int), stream);

    // W transpose+convert first (independent of LSTMs)
    conv_Wt<<<dim3(32, 16), dim3(256), 0, stream>>>(dns_W, Wt);

    const float* nul = nullptr;
    {   // encoder LSTM
        void* args[] = { (void*)&enc_emb, (void*)&x, (void*)&enc_Wx, (void*)&enc_Wh,
                         (void*)&enc_b, (void*)&nul, (void*)&nul,
                         (void*)&Hbuf, (void*)&ehp, (void*)&cfe, (void*)&bar0 };
        (void)hipLaunchCooperativeKernel(reinterpret_cast<void*>(lstm_coop),
                                         dim3(GRID_LSTM), dim3(512), args, 0, stream);
    }
    {   // decoder LSTM: h0 = enc final h (ehp slot0), c0 = enc final c
        const float* h0 = ehp;
        const float* c0 = cfe;
        void* args[] = { (void*)&dec_emb, (void*)&y, (void*)&dec_Wx, (void*)&dec_Wh,
                         (void*)&dec_b, (void*)&h0, (void*)&c0,
                         (void*)&Sbuf, (void*)&dhp, (void*)&cfd, (void*)&bar1 };
        (void)hipLaunchCooperativeKernel(reinterpret_cast<void*>(lstm_coop),
                                         dim3(GRID_LSTM), dim3(512), args, 0, stream);
    }
    attn_kernel<<<dim3(NB * 32), dim3(256), 0, stream>>>(Sbuf, Hbuf, ehp, Abuf);
    conv_yo<<<dim3(4096), dim3(256), 0, stream>>>(Sbuf, Abuf, yo);
    dense_mfma<<<dim3(16, 64), dim3(256), 0, stream>>>(yo, Wt, dns_b, out);
    softmax_rows<<<dim3(NB * NT), dim3(256), 0, stream>>>(out);
}

// Round 5
// 1620.856 us; speedup vs baseline: 2.1783x; 2.1783x over previous
//
#include <hip/hip_runtime.h>
#include <math.h>

#define NB 64       // batch
#define NT 128      // time steps
#define NE 64       // embedding
#define NU 512      // units
#define NG 2048     // 4*U
#define NV 2000     // vocab
#define BU (NB*NU)
#define GRID_LSTM 256

typedef __attribute__((ext_vector_type(8))) short bf16x8;
typedef __attribute__((ext_vector_type(4))) float f32x4;
typedef __attribute__((ext_vector_type(8))) unsigned short u16x8;

__device__ __forceinline__ unsigned short f2bf(float x) {
    unsigned int u = __float_as_uint(x);
    u += 0x7FFFu + ((u >> 16) & 1u);
    return (unsigned short)(u >> 16);
}

__device__ __forceinline__ float fsigmoid(float x) {
    return __builtin_amdgcn_rcpf(1.f + __expf(-x));
}
__device__ __forceinline__ float ftanh(float x) {
    return 1.f - 2.f * __builtin_amdgcn_rcpf(__expf(2.f * x) + 1.f);
}

// ---------------------------------------------------------------------------
// Cooperative LSTM: 256 blocks x 512 threads, 8 independent groups of 32
// blocks (group rg = bk&7 owns batch rows 8rg..8rg+7; cgi = bk>>3 owns units
// u0..u0+16). Wave wv owns k-slice [64wv,64wv+64). Wh in VGPRs.
//
// Per-step sync (the R4 poll-storm fix): h published via agent-scope relaxed
// stores (coherent at Infinity Cache, no L2 writeback needed), per-thread
// vmcnt(0), barrier, then ONE flag store per block (contention-free slots)
// and ONE polling wave per block (wave 0 reads the group's 32 flags + 5-shfl
// min-reduce) while waves 1-7 wait at s_barrier. Hout HBM store is issued
// AFTER the flag publish so its latency drains during the poll window.
// ---------------------------------------------------------------------------
__global__ __launch_bounds__(512, 1)
void lstm_coop(const float* __restrict__ emb, const int* __restrict__ ids,
               const float* __restrict__ Wx, const float* __restrict__ Wh,
               const float* __restrict__ bias,
               const float* __restrict__ h0, const float* __restrict__ c0,
               float* __restrict__ Hout, float* __restrict__ hping,
               float* __restrict__ cfin, unsigned int* __restrict__ flags)
{
    __shared__ float psum[8][8][64];           // 16 KB
    __shared__ float hlds[8][512];             // 16 KB

    const int tid  = threadIdx.x;
    const int wv   = tid >> 6;                 // 0..7 k-slice
    const int cl   = tid & 63;
    const int bk   = blockIdx.x;
    const int rg   = bk & 7;                   // group (8 groups x 32 blocks)
    const int cgi  = bk >> 3;                  // 0..31 unit slice
    const int brow0 = rg * 8;
    const int u0    = cgi * 16;
    const int gate  = cl >> 4;
    const int uu_c  = cl & 15;
    const int colg  = gate * 512 + u0 + uu_c;

    float w[64];
#pragma unroll
    for (int kk = 0; kk < 64; ++kk) w[kk] = Wh[(size_t)(wv * 64 + kk) * NG + colg];
    float wx[8];
#pragma unroll
    for (int ee = 0; ee < 8; ++ee) wx[ee] = Wx[(size_t)(wv * 8 + ee) * NG + colg];

    const int bl  = tid >> 4;                  // tid<128: row
    const int uug = tid & 15;
    float creg = 0.f;
    float b4[4] = {0.f, 0.f, 0.f, 0.f};
    if (tid < 128) {
#pragma unroll
        for (int g = 0; g < 4; ++g) b4[g] = bias[g * 512 + u0 + uug];
        if (c0) creg = c0[(brow0 + bl) * NU + u0 + uug];
    }

    // stage h(0): each wave stages exactly its k-slice (cols 64wv..64wv+63)
    {
        const int col = wv * 64 + cl;
#pragma unroll
        for (int b = 0; b < 8; ++b)
            hlds[b][col] = h0 ? h0[(brow0 + b) * NU + col] : 0.f;
    }
    unsigned int* fl = flags + rg * 64;
    __syncthreads();

    for (int t = 0; t < NT; ++t) {
        // ---- z partial: own k-slice from hlds (broadcast LDS reads)
        float acc[8];
#pragma unroll
        for (int b = 0; b < 8; ++b) {
            const float4* hb4 = reinterpret_cast<const float4*>(&hlds[b][wv * 64]);
            float a0 = 0.f, a1 = 0.f, a2 = 0.f, a3 = 0.f;
#pragma unroll
            for (int k4 = 0; k4 < 16; k4 += 4) {
                float4 v0 = hb4[k4 + 0];
                a0 += v0.x * w[4 * k4 + 0] + v0.y * w[4 * k4 + 1] + v0.z * w[4 * k4 + 2] + v0.w * w[4 * k4 + 3];
                float4 v1 = hb4[k4 + 1];
                a1 += v1.x * w[4 * k4 + 4] + v1.y * w[4 * k4 + 5] + v1.z * w[4 * k4 + 6] + v1.w * w[4 * k4 + 7];
                float4 v2 = hb4[k4 + 2];
                a2 += v2.x * w[4 * k4 + 8] + v2.y * w[4 * k4 + 9] + v2.z * w[4 * k4 + 10] + v2.w * w[4 * k4 + 11];
                float4 v3 = hb4[k4 + 3];
                a3 += v3.x * w[4 * k4 + 12] + v3.y * w[4 * k4 + 13] + v3.z * w[4 * k4 + 14] + v3.w * w[4 * k4 + 15];
            }
            const int idb = ids[(brow0 + b) * NT + t];
            const float4* eb = reinterpret_cast<const float4*>(emb + (size_t)idb * NE + wv * 8);
            float4 e0 = eb[0], e1 = eb[1];
            a0 += e0.x * wx[0] + e0.y * wx[1] + e0.z * wx[2] + e0.w * wx[3];
            a1 += e1.x * wx[4] + e1.y * wx[5] + e1.z * wx[6] + e1.w * wx[7];
            acc[b] = (a0 + a1) + (a2 + a3);
        }
#pragma unroll
        for (int b = 0; b < 8; ++b) psum[wv][b][cl] = acc[b];
        __syncthreads();                       // #1: psum complete

        float h_ = 0.f;
        if (tid < 128) {
            float z[4];
#pragma unroll
            for (int g = 0; g < 4; ++g) {
                float s = b4[g];
#pragma unroll
                for (int w8 = 0; w8 < 8; ++w8) s += psum[w8][bl][g * 16 + uug];
                z[g] = s;
            }
            const float i_ = fsigmoid(z[0]);
            const float f_ = fsigmoid(z[1]);
            const float g_ = ftanh(z[2]);
            const float o_ = fsigmoid(z[3]);
            creg = f_ * creg + i_ * g_;
            h_ = o_ * ftanh(creg);
            float* hw = hping + ((t + 1) & 1) * BU;
            __hip_atomic_store(&hw[(brow0 + bl) * NU + u0 + uug], h_,
                               __ATOMIC_RELAXED, __HIP_MEMORY_SCOPE_AGENT);
        }
        if (t == NT - 1) {
            if (tid < 128)
                Hout[((size_t)(brow0 + bl) * NT + t) * NU + u0 + uug] = h_;
            break;                             // final h/c flushed at kernel end
        }

        if (tid < 128)
            asm volatile("s_waitcnt vmcnt(0)" ::: "memory");  // h at coherence pt
        __syncthreads();                       // #2: all h stores complete

        if (tid == 0)
            __hip_atomic_store(&fl[cgi], (unsigned)(t + 1),
                               __ATOMIC_RELAXED, __HIP_MEMORY_SCOPE_AGENT);
        if (tid < 128)                         // off critical path: drains during poll
            Hout[((size_t)(brow0 + bl) * NT + t) * NU + u0 + uug] = h_;

        if (wv == 0) {                         // single polling wave per block
            const unsigned target = (unsigned)(t + 1);
            while (true) {
                unsigned v = __hip_atomic_load(&fl[cl & 31], __ATOMIC_RELAXED,
                                               __HIP_MEMORY_SCOPE_AGENT);
#pragma unroll
                for (int o = 16; o; o >>= 1) {
                    unsigned v2 = (unsigned)__shfl_xor((int)v, o);
                    v = v2 < v ? v2 : v;
                }
                if (v >= target) break;
                __builtin_amdgcn_s_sleep(1);
            }
        }
        __syncthreads();                       // #3: release all waves

        // ---- reload own h slice (write-read same wave: no barrier after)
        {
            const float* hr = hping + ((t + 1) & 1) * BU + (size_t)brow0 * NU;
            const int col = wv * 64 + cl;
            float tmp[8];
#pragma unroll
            for (int b = 0; b < 8; ++b)
                tmp[b] = __hip_atomic_load(const_cast<float*>(&hr[b * NU + col]),
                                           __ATOMIC_RELAXED, __HIP_MEMORY_SCOPE_AGENT);
#pragma unroll
            for (int b = 0; b < 8; ++b) hlds[b][col] = tmp[b];
        }
    }
    if (tid < 128) cfin[(brow0 + bl) * NU + u0 + uug] = creg;
}

// ---------------------------------------------------------------------------
// Attention: one wave per (b,q), registers + butterflies.
// ---------------------------------------------------------------------------
__global__ __launch_bounds__(256)
void attn_kernel(const float* __restrict__ S, const float* __restrict__ Hbuf,
                 const float* __restrict__ s0, float* __restrict__ A)
{
    const int tid  = threadIdx.x;
    const int wv   = tid >> 6;
    const int lane = tid & 63;
    const int b    = blockIdx.x >> 5;
    const int q    = (blockIdx.x & 31) * 4 + wv;

    const float* qrow = (q == 0) ? (s0 + (size_t)b * NU)
                                 : (S + ((size_t)b * NT + (q - 1)) * NU);
    const float4* q4 = reinterpret_cast<const float4*>(qrow);
    const float4 qa = q4[lane], qb = q4[64 + lane];
    const float4* Hb = reinterpret_cast<const float4*>(Hbuf + (size_t)b * NT * NU);

    float sr0 = 0.f, sr1 = 0.f;
    for (int k = 0; k < NT; ++k) {
        const float4* hk = Hb + (size_t)k * 128;
        float4 ha = hk[lane], hc = hk[64 + lane];
        float d = qa.x * ha.x + qa.y * ha.y + qa.z * ha.z + qa.w * ha.w
                + qb.x * hc.x + qb.y * hc.y + qb.z * hc.z + qb.w * hc.w;
#pragma unroll
        for (int o = 32; o; o >>= 1) d += __shfl_xor(d, o);
        if ((k & 63) == lane) { if (k < 64) sr0 = d; else sr1 = d; }
        if ((k & 31) == 31) __syncthreads();
    }

    float m = fmaxf(sr0, sr1);
#pragma unroll
    for (int o = 32; o; o >>= 1) m = fmaxf(m, __shfl_xor(m, o));
    float e0 = expf(sr0 - m), e1 = expf(sr1 - m);
    float s = e0 + e1;
#pragma unroll
    for (int o = 32; o; o >>= 1) s += __shfl_xor(s, o);
    const float inv = 1.f / s;
    e0 *= inv; e1 *= inv;

    float4 acc0 = {0.f, 0.f, 0.f, 0.f}, acc1 = {0.f, 0.f, 0.f, 0.f};
    for (int k = 0; k < 64; ++k) {
        const float wk = __shfl(e0, k);
        const float4* hk = Hb + (size_t)k * 128;
        float4 ha = hk[lane], hc = hk[64 + lane];
        acc0.x += wk * ha.x; acc0.y += wk * ha.y; acc0.z += wk * ha.z; acc0.w += wk * ha.w;
        acc1.x += wk * hc.x; acc1.y += wk * hc.y; acc1.z += wk * hc.z; acc1.w += wk * hc.w;
        if ((k & 31) == 31) __syncthreads();
    }
    for (int k = 0; k < 64; ++k) {
        const float wk = __shfl(e1, k);
        const float4* hk = Hb + (size_t)(64 + k) * 128;
        float4 ha = hk[lane], hc = hk[64 + lane];
        acc0.x += wk * ha.x; acc0.y += wk * ha.y; acc0.z += wk * ha.z; acc0.w += wk * ha.w;
        acc1.x += wk * hc.x; acc1.y += wk * hc.y; acc1.z += wk * hc.z; acc1.w += wk * hc.w;
        if ((k & 31) == 31) __syncthreads();
    }
    float4* Aq = reinterpret_cast<float4*>(A + ((size_t)b * NT + q) * NU);
    Aq[lane] = acc0;
    Aq[64 + lane] = acc1;
}

// ---------------------------------------------------------------------------
// Convert yo=[S|A] (fp32) -> bf16 [8192][1024] (aliases Hbuf; runs after attn)
// ---------------------------------------------------------------------------
__global__ __launch_bounds__(256)
void conv_yo(const float* __restrict__ S, const float* __restrict__ A,
             unsigned short* __restrict__ yo)
{
    const int base = (blockIdx.x * 256 + threadIdx.x) * 8;
    const int row = base >> 10;
    const int col = base & 1023;
    const float* src = (col < 512) ? (S + (size_t)row * NU + col)
                                   : (A + (size_t)row * NU + (col - 512));
    const float4 v0 = reinterpret_cast<const float4*>(src)[0];
    const float4 v1 = reinterpret_cast<const float4*>(src)[1];
    u16x8 o;
    o[0] = f2bf(v0.x); o[1] = f2bf(v0.y); o[2] = f2bf(v0.z); o[3] = f2bf(v0.w);
    o[4] = f2bf(v1.x); o[5] = f2bf(v1.y); o[6] = f2bf(v1.z); o[7] = f2bf(v1.w);
    *reinterpret_cast<u16x8*>(yo + base) = o;
}

// ---------------------------------------------------------------------------
// Transpose dense_W [1024][2000] fp32 -> Wt [2048][1024] bf16 (pad rows zero)
// ---------------------------------------------------------------------------
__global__ __launch_bounds__(256)
void conv_Wt(const float* __restrict__ W, unsigned short* __restrict__ Wt)
{
    __shared__ float lt[64][65];
    const int tid = threadIdx.x;
    const int c0 = blockIdx.x * 64;
    const int k0 = blockIdx.y * 64;
#pragma unroll
    for (int j = 0; j < 16; ++j) {
        const int lin = tid + 256 * j;
        const int kk = lin >> 6, cc = lin & 63;
        const int c = c0 + cc;
        lt[cc][kk] = (c < NV) ? W[(size_t)(k0 + kk) * NV + c] : 0.f;
    }
    __syncthreads();
    const int c = tid >> 2, kseg = tid & 3;
    unsigned short tmp[16];
#pragma unroll
    for (int m = 0; m < 16; ++m)
        tmp[m] = f2bf(lt[c][kseg * 16 + m]);
    unsigned short* dst = Wt + (size_t)(c0 + c) * 1024 + k0 + kseg * 16;
    *reinterpret_cast<u16x8*>(dst)     = *reinterpret_cast<u16x8*>(tmp);
    *reinterpret_cast<u16x8*>(dst + 8) = *reinterpret_cast<u16x8*>(tmp + 8);
}

// ---------------------------------------------------------------------------
// Dense via bf16 MFMA: out[8192][2000] = yo[8192][1024] x W[1024][2000] + b.
// ---------------------------------------------------------------------------
__global__ __launch_bounds__(256)
void dense_mfma(const unsigned short* __restrict__ yo,
                const unsigned short* __restrict__ Wt,
                const float* __restrict__ bias, float* __restrict__ out)
{
    __shared__ unsigned short Asm[128][40];
    __shared__ unsigned short Bsm[128][40];
    const int tid  = threadIdx.x;
    const int wave = tid >> 6, lane = tid & 63;
    const int wm = wave >> 1, wn = wave & 1;
    const int r0 = blockIdx.y * 128, c0 = blockIdx.x * 128;
    const int rr = lane & 15, kh = lane >> 4;

    f32x4 acc[4][4];
#pragma unroll
    for (int m = 0; m < 4; ++m)
#pragma unroll
        for (int n = 0; n < 4; ++n) acc[m][n] = (f32x4){0.f, 0.f, 0.f, 0.f};

    for (int k0 = 0; k0 < 1024; k0 += 32) {
        __syncthreads();
#pragma unroll
        for (int h = 0; h < 2; ++h) {
            const int row = (tid >> 2) + h * 64, seg = tid & 3;
            *reinterpret_cast<uint4*>(&Asm[row][seg * 8]) =
                *reinterpret_cast<const uint4*>(yo + (size_t)(r0 + row) * 1024 + k0 + seg * 8);
            *reinterpret_cast<uint4*>(&Bsm[row][seg * 8]) =
                *reinterpret_cast<const uint4*>(Wt + (size_t)(c0 + row) * 1024 + k0 + seg * 8);
        }
        __syncthreads();
        bf16x8 af[4], bfr[4];
#pragma unroll
        for (int m = 0; m < 4; ++m)
            af[m] = *reinterpret_cast<const bf16x8*>(&Asm[wm * 64 + m * 16 + rr][kh * 8]);
#pragma unroll
        for (int n = 0; n < 4; ++n)
            bfr[n] = *reinterpret_cast<const bf16x8*>(&Bsm[wn * 64 + n * 16 + rr][kh * 8]);
#pragma unroll
        for (int m = 0; m < 4; ++m)
#pragma unroll
            for (int n = 0; n < 4; ++n)
                acc[m][n] = __builtin_amdgcn_mfma_f32_16x16x32_bf16(af[m], bfr[n], acc[m][n], 0, 0, 0);
    }

#pragma unroll
    for (int m = 0; m < 4; ++m) {
#pragma unroll
        for (int n = 0; n < 4; ++n) {
            const int c = c0 + wn * 64 + n * 16 + rr;
            if (c < NV) {
                const float bc = bias[c];
#pragma unroll
                for (int reg = 0; reg < 4; ++reg) {
                    const int r = r0 + wm * 64 + m * 16 + kh * 4 + reg;
                    out[(size_t)r * NV + c] = acc[m][n][reg] + bc;
                }
            }
        }
    }
}

// ---------------------------------------------------------------------------
// In-place row softmax over V=2000 logits.
// ---------------------------------------------------------------------------
__global__ __launch_bounds__(256)
void softmax_rows(float* __restrict__ out)
{
    __shared__ float red[4];
    const int t = threadIdx.x;
    float* row = out + (size_t)blockIdx.x * NV;

    float v[8];
    float m = -INFINITY;
#pragma unroll
    for (int i = 0; i < 8; ++i) {
        const int j = t + 256 * i;
        v[i] = (j < NV) ? row[j] : -INFINITY;
        m = fmaxf(m, v[i]);
    }
#pragma unroll
    for (int o = 32; o; o >>= 1) m = fmaxf(m, __shfl_xor(m, o));
    if ((t & 63) == 0) red[t >> 6] = m;
    __syncthreads();
    m = fmaxf(fmaxf(red[0], red[1]), fmaxf(red[2], red[3]));
    __syncthreads();

    float s = 0.f;
#pragma unroll
    for (int i = 0; i < 8; ++i) {
        const int j = t + 256 * i;
        if (j < NV) { v[i] = expf(v[i] - m); s += v[i]; }
    }
#pragma unroll
    for (int o = 32; o; o >>= 1) s += __shfl_xor(s, o);
    if ((t & 63) == 0) red[t >> 6] = s;
    __syncthreads();
    const float inv = 1.f / (red[0] + red[1] + red[2] + red[3]);
#pragma unroll
    for (int i = 0; i < 8; ++i) {
        const int j = t + 256 * i;
        if (j < NV) row[j] = v[i] * inv;
    }
}

// ---------------------------------------------------------------------------
extern "C" void kernel_launch(void* const* d_in, const int* in_sizes, int n_in,
                              void* d_out, int out_size, void* d_ws, size_t ws_size,
                              hipStream_t stream)
{
    const int*   x       = (const int*)  d_in[0];
    const int*   y       = (const int*)  d_in[1];
    const float* enc_emb = (const float*)d_in[2];
    const float* enc_Wx  = (const float*)d_in[3];
    const float* enc_Wh  = (const float*)d_in[4];
    const float* enc_b   = (const float*)d_in[5];
    const float* dec_emb = (const float*)d_in[6];
    const float* dec_Wx  = (const float*)d_in[7];
    const float* dec_Wh  = (const float*)d_in[8];
    const float* dec_b   = (const float*)d_in[9];
    const float* dns_W   = (const float*)d_in[10];
    const float* dns_b   = (const float*)d_in[11];
    float* out = (float*)d_out;

    float* ws   = (float*)d_ws;
    float* Hbuf = ws;                                  // [B,T,U] fp32 (later aliased by yo bf16)
    float* Sbuf = Hbuf + (size_t)NB * NT * NU;
    float* Abuf = Sbuf + (size_t)NB * NT * NU;
    unsigned short* Wt = (unsigned short*)(Abuf + (size_t)NB * NT * NU);  // [2048][1024] bf16
    float* ehp  = (float*)(Wt + (size_t)2048 * 1024);  // enc h ping-pong [2][B,U]
    float* dhp  = ehp + 2 * BU;
    float* cfe  = dhp + 2 * BU;
    float* cfd  = cfe + BU;
    unsigned int* bar0 = (unsigned int*)(cfd + BU);    // 512 flags enc
    unsigned int* bar1 = bar0 + 512;                   // 512 flags dec
    unsigned short* yo = (unsigned short*)Hbuf;        // bf16 [8192][1024], alias

    hipMemsetAsync(bar0, 0, 2 * 512 * sizeof(unsigned int), stream);

    // W transpose+convert first (independent of LSTMs)
    conv_Wt<<<dim3(32, 16), dim3(256), 0, stream>>>(dns_W, Wt);

    const float* nul = nullptr;
    {   // encoder LSTM
        void* args[] = { (void*)&enc_emb, (void*)&x, (void*)&enc_Wx, (void*)&enc_Wh,
                         (void*)&enc_b, (void*)&nul, (void*)&nul,
                         (void*)&Hbuf, (void*)&ehp, (void*)&cfe, (void*)&bar0 };
        (void)hipLaunchCooperativeKernel(reinterpret_cast<void*>(lstm_coop),
                                         dim3(GRID_LSTM), dim3(512), args, 0, stream);
    }
    {   // decoder LSTM: h0 = enc final h (ehp slot0), c0 = enc final c
        const float* h0 = ehp;
        const float* c0 = cfe;
        void* args[] = { (void*)&dec_emb, (void*)&y, (void*)&dec_Wx, (void*)&dec_Wh,
                         (void*)&dec_b, (void*)&h0, (void*)&c0,
                         (void*)&Sbuf, (void*)&dhp, (void*)&cfd, (void*)&bar1 };
        (void)hipLaunchCooperativeKernel(reinterpret_cast<void*>(lstm_coop),
                                         dim3(GRID_LSTM), dim3(512), args, 0, stream);
    }
    attn_kernel<<<dim3(NB * 32), dim3(256), 0, stream>>>(Sbuf, Hbuf, ehp, Abuf);
    conv_yo<<<dim3(4096), dim3(256), 0, stream>>>(Sbuf, Abuf, yo);
    dense_mfma<<<dim3(16, 64), dim3(256), 0, stream>>>(yo, Wt, dns_b, out);
    softmax_rows<<<dim3(NB * NT), dim3(256), 0, stream>>>(out);
}